// Round 6
// baseline (311.217 us; speedup 1.0000x reference)
//
#include <hip/hip_runtime.h>
#include <math.h>

constexpr int M   = 64;       // rows of phi / Y
constexpr int NR  = 256;      // rows of X
constexpr int KK  = NR + M;   // 320: stacked K dim  [W | Z] · [X ; Y]
constexpr int NC  = 131072;   // columns
constexpr int BN  = 32;       // columns per block
constexpr float THR = 0.1f;

typedef __bf16 bf16x8 __attribute__((ext_vector_type(8)));
typedef float  f32x4  __attribute__((ext_vector_type(4)));
typedef unsigned int u32;

static __device__ __forceinline__ unsigned short f2bf(float f) {
    unsigned int u = __float_as_uint(f);
    u += 0x7FFFu + ((u >> 16) & 1u);        // round-to-nearest-even
    return (unsigned short)(u >> 16);
}

// forced-issue 16B global load: asm volatile cannot be sunk/reordered vs other
// volatiles, "=v" keeps the result register-resident -> deep outstanding loads.
static __device__ __forceinline__ void gload16(f32x4& d, const float* p) {
    asm volatile("global_load_dwordx4 %0, %1, off" : "=v"(d) : "v"(p));
}
template<int N> static __device__ __forceinline__ void waitv() {
    asm volatile("s_waitcnt vmcnt(%0)" :: "i"(N));
    __builtin_amdgcn_sched_barrier(0);      // rule #18: stop hoisting past the wait
}

// A stored fragment-linear: chunk ((wave*10 + kb)*4 + mt) of 512 bf16 (1 KiB);
// element (lane*8 + j); lane = quad*16 + nlo.
// (i = wave*64 + mt*16 + nlo, kk = kb*32 + quad*8 + j)
static __device__ __forceinline__ int a_off(int i, int kk) {
    const int wave = i >> 6, mt = (i >> 4) & 3, nlo = i & 15;
    const int kb = kk >> 5, quad = (kk >> 3) & 3, j = kk & 7;
    return (((wave * 10 + kb) * 4 + mt) << 9) + ((quad * 16 + nlo) << 3) + j;
}

__global__ __launch_bounds__(256)
void k_copy_phi(const float* __restrict__ phi, float* __restrict__ out)
{
    int i = blockIdx.x * 256 + threadIdx.x;
    out[i] = phi[i];
}

// Build A = [ I - s*phi^T*phi  |  s*phi^T ]  (256 x 320, bf16) in ws,
// stored fragment-linear (a_off). Block i computes row i.
__global__ __launch_bounds__(256)
void k_prep(const float* __restrict__ phi, const float* __restrict__ step,
            unsigned short* __restrict__ A)
{
    __shared__ float ph[M * NR];            // 64 KiB, phi row-major 64x256
    const int i = blockIdx.x, j = threadIdx.x;
    for (int t = j; t < M * NR; t += 256) ph[t] = phi[t];
    __syncthreads();
    const float s = step[0];
    float d = 0.f;
    #pragma unroll
    for (int m = 0; m < M; ++m)
        d = fmaf(ph[m * NR + i], ph[m * NR + j], d);
    float w = ((i == j) ? 1.f : 0.f) - s * d;
    A[a_off(i, j)] = f2bf(w);
    if (j < M) A[a_off(i, NR + j)] = f2bf(s * ph[j * NR + i]);
}

// U = A[256x320] * [X;Y][320xN], threshold, copy for cols >= k.
// BN=32, ~5-6 blocks/CU. Staging burst is FORCED deep via inline-asm loads
// (10 x 1KB/wave issued back-to-back, counted vmcnt waits): R1/R2/R5 proved
// the compiler otherwise sinks (VGPR=36) or spills (VGPR=128) the burst,
// capping outstanding HBM bytes and pinning BW at ~2 TB/s.
// Convert window contains EXACTLY these 10 vmem ops (a_cur prefetch is issued
// after the convert loop, fenced by sched_barrier) so vmcnt counts are exact:
// before convert 'it' (consumes loads 2it+1,2it+2) wait vmcnt(8-2it).
// LDS B: bf16, XOR-swizzled: byte(kb,n,kl) = kb*2048 + n*64 + kl*2,
// then ^ ((n&14)<<3) -> b128 fragment reads <=2-way (free), staging
// ds_write_b32 exactly 2-way (free).
__global__ __launch_bounds__(256, 4)
void k_gemm(const unsigned short* __restrict__ A,
            const float* __restrict__ X,
            const float* __restrict__ Y,
            const int*   __restrict__ idxp,
            float* __restrict__ outX)
{
    const int k   = idxp[0] + 1;
    const int n0  = blockIdx.x * BN;
    const int tid = threadIdx.x;

    if (n0 >= k) {                           // pure-copy fast path: batch loads
        const int c8 = tid & 7, rg = tid >> 3;
        f32x4 t[8];
        #pragma unroll
        for (int j = 0; j < 8; ++j) {
            const int r = rg + 32 * j;
            gload16(t[j], X + (size_t)r * NC + n0 + 4 * c8);
        }
        waitv<0>();
        #pragma unroll
        for (int j = 0; j < 8; ++j) {
            const int r = rg + 32 * j;
            *(f32x4*)(outX + (size_t)r * NC + n0 + 4 * c8) = t[j];
        }
        return;
    }

    __shared__ u32 Bu32[10 * 2048 / 4];      // 20480 B

    const int c8 = tid & 7, rp = (tid >> 3) & 15, kh = tid >> 7;
    const int lane = tid & 63, wave = tid >> 6;
    const int quad = lane >> 4, nlo = lane & 15;

    // ---- forced burst: 10 x 16B loads issued back-to-back ----
    f32x4 v0[5], v1[5];
    __builtin_amdgcn_sched_barrier(0);
    #pragma unroll
    for (int it = 0; it < 5; ++it) {
        const int kb = 2 * it + kh;
        const int r0 = kb * 32 + 2 * rp;     // even row; pair never crosses X/Y seam
        const float *s0, *s1;
        if (r0 < NR) { s0 = X + (size_t)r0 * NC;        s1 = X + (size_t)(r0 + 1) * NC; }
        else         { s0 = Y + (size_t)(r0 - NR) * NC; s1 = Y + (size_t)(r0 + 1 - NR) * NC; }
        gload16(v0[it], s0 + n0 + 4 * c8);
        gload16(v1[it], s1 + n0 + 4 * c8);
    }
    __builtin_amdgcn_sched_barrier(0);

    // ---- convert + write swizzled LDS, counted waits (exactly my 10 ops) ----
    #pragma unroll
    for (int it = 0; it < 5; ++it) {
        switch (it) {                        // loads 2it+1,2it+2 landed
            case 0: waitv<8>(); break;
            case 1: waitv<6>(); break;
            case 2: waitv<4>(); break;
            case 3: waitv<2>(); break;
            default: waitv<0>(); break;
        }
        const int kb  = 2 * it + kh;
        const int kl2 = 4 * rp;              // byte offset of row 2*rp (kl*2)
        #pragma unroll
        for (int c = 0; c < 4; ++c) {
            const int n = 4 * c8 + c;
            const int byteoff = (kb * 2048 + n * 64 + kl2) ^ ((n & 14) << 3);
            Bu32[byteoff >> 2] =
                (u32)f2bf(v0[it][c]) | ((u32)f2bf(v1[it][c]) << 16);
        }
    }

    // ---- A kb=0 prefetch (L2-hot); overlaps barrier + acc init ----
    const unsigned short* Abase = A + ((wave * 40) << 9) + (lane << 3);
    bf16x8 a_cur[4], a_nxt[4];
    #pragma unroll
    for (int mt = 0; mt < 4; ++mt)
        a_cur[mt] = *(const bf16x8*)(Abase + (mt << 9));

    __syncthreads();

    f32x4 acc[4][2];
    #pragma unroll
    for (int mt = 0; mt < 4; ++mt)
        #pragma unroll
        for (int nt = 0; nt < 2; ++nt)
            acc[mt][nt] = (f32x4){0.f, 0.f, 0.f, 0.f};

    // swz for reads: n = nlo + nt*16 -> ((n>>1)&7)<<4 == ((nlo>>1)&7)<<4 (nt-independent)
    const char* Bbase = (const char*)Bu32 +
                        (((unsigned)(nlo * 64 + quad * 16)) ^ ((nlo & 14) << 3));

    #pragma unroll
    for (int kb = 0; kb < 10; ++kb) {
        if (kb < 9) {                        // 1-deep A prefetch across kb
            #pragma unroll
            for (int mt = 0; mt < 4; ++mt)
                a_nxt[mt] = *(const bf16x8*)(Abase + (((kb + 1) * 4 + mt) << 9));
        }
        bf16x8 bfr[2];
        #pragma unroll
        for (int nt = 0; nt < 2; ++nt)
            bfr[nt] = *(const bf16x8*)(Bbase + kb * 2048 + nt * 1024);
        #pragma unroll
        for (int mt = 0; mt < 4; ++mt)
            #pragma unroll
            for (int nt = 0; nt < 2; ++nt)
                acc[mt][nt] = __builtin_amdgcn_mfma_f32_16x16x32_bf16(
                    a_cur[mt], bfr[nt], acc[mt][nt], 0, 0, 0);
        #pragma unroll
        for (int mt = 0; mt < 4; ++mt) a_cur[mt] = a_nxt[mt];
    }

    // ---- epilogue: threshold + boundary copy + store ----
    const int mbase = wave * 64;
    const bool boundary = (n0 + BN > k);
    #pragma unroll
    for (int mt = 0; mt < 4; ++mt) {
        #pragma unroll
        for (int nt = 0; nt < 2; ++nt) {
            const int col = n0 + nt * 16 + nlo;
            #pragma unroll
            for (int reg = 0; reg < 4; ++reg) {
                const int row = mbase + mt * 16 + quad * 4 + reg;
                float v = acc[mt][nt][reg];
                v = (fabsf(v) > THR) ? v : 0.f;
                if (boundary && col >= k) v = X[(size_t)row * NC + col];
                outX[(size_t)row * NC + col] = v;
            }
        }
    }
}

extern "C" void kernel_launch(void* const* d_in, const int* in_sizes, int n_in,
                              void* d_out, int out_size, void* d_ws, size_t ws_size,
                              hipStream_t stream)
{
    const float* phi  = (const float*)d_in[0];
    const float* X    = (const float*)d_in[1];
    const float* Y    = (const float*)d_in[2];
    const float* step = (const float*)d_in[3];
    const int*   idx  = (const int*)d_in[4];
    float* out = (float*)d_out;
    unsigned short* A = (unsigned short*)d_ws;   // 256*320*2 = 160 KiB, fragment-linear

    k_copy_phi<<<(M * NR) / 256, 256, 0, stream>>>(phi, out);
    k_prep<<<NR, 256, 0, stream>>>(phi, step, A);
    k_gemm<<<NC / BN, 256, 0, stream>>>(A, X, Y, idx, out + M * NR);
}

// Round 7
// 287.274 us; speedup vs baseline: 1.0833x; 1.0833x over previous
//
#include <hip/hip_runtime.h>
#include <math.h>

constexpr int M   = 64;       // rows of phi / Y
constexpr int NR  = 256;      // rows of X
constexpr int KK  = NR + M;   // 320: stacked K dim  [W | Z] · [X ; Y]
constexpr int NC  = 131072;   // columns
constexpr int BN  = 256;      // columns per block: 1 KB contiguous per row
constexpr int GRID = NC / BN; // 512
constexpr float THR = 0.1f;

typedef __bf16 bf16x8 __attribute__((ext_vector_type(8)));
typedef float  f32x4  __attribute__((ext_vector_type(4)));
typedef unsigned int u32;

static __device__ __forceinline__ unsigned short f2bf(float f) {
    unsigned int u = __float_as_uint(f);
    u += 0x7FFFu + ((u >> 16) & 1u);        // round-to-nearest-even
    return (unsigned short)(u >> 16);
}

// async global->LDS DMA: 64 lanes x 16 B = one contiguous 1 KB run per instr.
// Modeled by the compiler's waitcnt pass (unlike R6's asm loads) -> exact counts.
static __device__ __forceinline__ void gload_lds16(const float* g, void* l) {
    __builtin_amdgcn_global_load_lds(
        (const __attribute__((address_space(1))) u32*)g,
        (__attribute__((address_space(3))) u32*)l, 16, 0, 0);
}
template<int N> static __device__ __forceinline__ void waitv() {
    asm volatile("s_waitcnt vmcnt(%0)" :: "i"(N));
    __builtin_amdgcn_sched_barrier(0);      // rule #18
}
static __device__ __forceinline__ void waitl0() {
    asm volatile("s_waitcnt lgkmcnt(0)" ::: "memory");
    __builtin_amdgcn_sched_barrier(0);
}
static __device__ __forceinline__ void barrier_raw() {   // no vmcnt drain
    asm volatile("" ::: "memory");
    __builtin_amdgcn_s_barrier();
    asm volatile("" ::: "memory");
}

// A stored fragment-linear: chunk ((wr*10 + kb)*4 + mt) of 512 bf16 (1 KiB);
// element (lane*8 + j); (i = wr*64 + mt*16 + nlo, kk = kb*32 + quad*8 + j)
static __device__ __forceinline__ int a_off(int i, int kk) {
    const int wr = i >> 6, mt = (i >> 4) & 3, nlo = i & 15;
    const int kb = kk >> 5, quad = (kk >> 3) & 3, j = kk & 7;
    return (((wr * 10 + kb) * 4 + mt) << 9) + ((quad * 16 + nlo) << 3) + j;
}

__global__ __launch_bounds__(256)
void k_copy_phi(const float* __restrict__ phi, float* __restrict__ out)
{
    int i = blockIdx.x * 256 + threadIdx.x;
    out[i] = phi[i];
}

__global__ __launch_bounds__(256)
void k_prep(const float* __restrict__ phi, const float* __restrict__ step,
            unsigned short* __restrict__ A)
{
    __shared__ float ph[M * NR];            // 64 KiB, phi row-major 64x256
    const int i = blockIdx.x, j = threadIdx.x;
    for (int t = j; t < M * NR; t += 256) ph[t] = phi[t];
    __syncthreads();
    const float s = step[0];
    float d = 0.f;
    #pragma unroll
    for (int m = 0; m < M; ++m)
        d = fmaf(ph[m * NR + i], ph[m * NR + j], d);
    float w = ((i == j) ? 1.f : 0.f) - s * d;
    A[a_off(i, j)] = f2bf(w);
    if (j < M) A[a_off(i, NR + j)] = f2bf(s * ph[j * NR + i]);
}

// U = A[256x320] * [X;Y][320xN], threshold, copy for cols >= k.
// BN=256, 512 thr / 8 waves (wr=wave>>1 rows, wc=wave&1 col-half).
// Per kb (32 k-rows): DMA f32 panel (32 x 1KB linear runs, double-buffered)
// -> each wave converts ITS OWN 4 DMA'd rows to swizzled bf16 (vmcnt(0) is
// per-wave self-consistent, no barrier needed before convert) -> one barrier
// -> MFMA. A-frags loaded BEFORE the next DMA issue so compiler A-waits are
// vmcnt(4), keeping the next panel in flight through the MFMA phase.
// LDS: fpanel 2x32KB f32 + bpanel 2x16KB bf16 = 96 KB -> 1 block/CU.
// bf16 swizzle: byte(kl,n) = n*64 + kl*2, ^ ((n&14)<<3): frag b128 reads
// <=2-way (free), staging writes ~4-8-way (minor, validated R5).
__global__ __launch_bounds__(512)
void k_gemm(const unsigned short* __restrict__ A,
            const float* __restrict__ X,
            const float* __restrict__ Y,
            const int*   __restrict__ idxp,
            float* __restrict__ outX)
{
    const int k   = idxp[0] + 1;
    const int bid = blockIdx.x;
    const int n0  = ((bid & 7) * (GRID / 8) + (bid >> 3)) * BN;  // XCD-bijective
    const int tid = threadIdx.x;

    if (n0 >= k) {                           // pure-copy: fully linear sweep
        for (int j = 0; j < 32; ++j) {
            const int idx = tid + 512 * j;
            const int r = idx >> 6, c4 = (idx & 63) * 4;
            *(f32x4*)(outX + (size_t)r * NC + n0 + c4) =
                *(const f32x4*)(X + (size_t)r * NC + n0 + c4);
        }
        return;
    }

    __shared__ __align__(16) unsigned char lds_raw[98304];
    char* fpan = (char*)lds_raw;             // 2 x 32768 B f32 panels
    char* bpan = (char*)lds_raw + 65536;     // 2 x 16384 B bf16 panels

    const int lane = tid & 63, wave = tid >> 6;
    const int wr = wave >> 1, wc = wave & 1;
    const int quad = lane >> 4, nlo = lane & 15;
    const int rp = tid >> 5;                 // 0..15: row pair (== wave's own rows)
    const int ca = (tid & 31) * 4;           // col quad 0..124

    auto issue = [&](int kb, int buf) {      // DMA 4 rows (this wave's rows)
        #pragma unroll
        for (int q = 0; q < 4; ++q) {
            const int r  = wave * 4 + q;
            const int gr = kb * 32 + r;
            const float* src = (gr < NR ? X + (size_t)gr * NC
                                        : Y + (size_t)(gr - NR) * NC) + n0;
            gload_lds16(src + lane * 4, fpan + buf * 32768 + r * 1024);
        }
    };

    issue(0, 0);

    f32x4 acc[4][8];
    #pragma unroll
    for (int mt = 0; mt < 4; ++mt)
        #pragma unroll
        for (int nt = 0; nt < 8; ++nt)
            acc[mt][nt] = (f32x4){0.f, 0.f, 0.f, 0.f};

    const unsigned short* Abase = A + ((wr * 40) << 9) + (lane << 3);
    // frag read: col n = 128wc+16nt+nlo -> swz bits depend only on nlo
    const char* Bfrag = bpan + wc * 8192 +
                        (((unsigned)(nlo * 64 + quad * 16)) ^ ((nlo & 14) << 3));

    #pragma unroll 2
    for (int kb = 0; kb < 10; ++kb) {
        const int c = kb & 1;
        waitv<0>();                          // my 4 DMA rows landed

        bf16x8 afr[4];                       // A frags BEFORE next DMA issue
        #pragma unroll
        for (int mt = 0; mt < 4; ++mt)
            afr[mt] = *(const bf16x8*)(Abase + (((kb << 2) + mt) << 9));
        __builtin_amdgcn_sched_barrier(0);   // keep afr older than issue()

        // ---- convert my own rows: f32 panel -> swizzled bf16 panel ----
        {
            const char* fb = fpan + c * 32768 + (size_t)(2 * rp) * 1024;
            f32x4 a0 = *(const f32x4*)(fb + ca * 4);
            f32x4 a1 = *(const f32x4*)(fb + 1024 + ca * 4);
            f32x4 b0 = *(const f32x4*)(fb + (ca + 128) * 4);
            f32x4 b1 = *(const f32x4*)(fb + 1024 + (ca + 128) * 4);
            char* bb = bpan + c * 16384;
            #pragma unroll
            for (int cc = 0; cc < 4; ++cc) {
                const int n1 = ca + cc, n2 = n1 + 128;
                const int o1 = (n1 * 64 + rp * 4) ^ ((n1 & 14) << 3);
                const int o2 = (n2 * 64 + rp * 4) ^ ((n2 & 14) << 3);
                *(u32*)(bb + o1) = (u32)f2bf(a0[cc]) | ((u32)f2bf(a1[cc]) << 16);
                *(u32*)(bb + o2) = (u32)f2bf(b0[cc]) | ((u32)f2bf(b1[cc]) << 16);
            }
        }
        waitl0();                            // my ds ops done before barrier
        if (kb < 9) issue(kb + 1, c ^ 1);    // next panel DMA: in flight across
        barrier_raw();                       //   barrier + whole MFMA phase

        // ---- MFMA on bpanel[c] (no new vmem; A-waits = vmcnt(4)) ----
        #pragma unroll
        for (int nt = 0; nt < 8; ++nt) {
            bf16x8 bfr = *(const bf16x8*)(Bfrag + c * 16384 + nt * 1024);
            #pragma unroll
            for (int mt = 0; mt < 4; ++mt)
                acc[mt][nt] = __builtin_amdgcn_mfma_f32_16x16x32_bf16(
                    afr[mt], bfr, acc[mt][nt], 0, 0, 0);
        }
    }

    // ---- epilogue: threshold + boundary copy + store (1 KB/row aggregate) ----
    const bool boundary = (n0 + BN > k);
    #pragma unroll
    for (int mt = 0; mt < 4; ++mt) {
        #pragma unroll
        for (int nt = 0; nt < 8; ++nt) {
            const int col = n0 + wc * 128 + nt * 16 + nlo;
            #pragma unroll
            for (int reg = 0; reg < 4; ++reg) {
                const int row = wr * 64 + mt * 16 + quad * 4 + reg;
                float v = acc[mt][nt][reg];
                v = (fabsf(v) > THR) ? v : 0.f;
                if (boundary && col >= k) v = X[(size_t)row * NC + col];
                outX[(size_t)row * NC + col] = v;
            }
        }
    }
}

extern "C" void kernel_launch(void* const* d_in, const int* in_sizes, int n_in,
                              void* d_out, int out_size, void* d_ws, size_t ws_size,
                              hipStream_t stream)
{
    const float* phi  = (const float*)d_in[0];
    const float* X    = (const float*)d_in[1];
    const float* Y    = (const float*)d_in[2];
    const float* step = (const float*)d_in[3];
    const int*   idx  = (const int*)d_in[4];
    float* out = (float*)d_out;
    unsigned short* A = (unsigned short*)d_ws;   // 256*320*2 = 160 KiB, fragment-linear

    k_copy_phi<<<(M * NR) / 256, 256, 0, stream>>>(phi, out);
    k_prep<<<NR, 256, 0, stream>>>(phi, step, A);
    k_gemm<<<GRID, 512, 0, stream>>>(A, X, Y, idx, out + M * NR);
}